// Round 23
// baseline (42.595 us; speedup 1.0000x reference)
//
#include <hip/hip_runtime.h>
#include <hip/hip_bf16.h>
#include <math.h>

#define NN    20000
#define NK    160000          // NN*8
#define NEDGE 320000
#define HID   256
#define INFEAT 128
#define EPSF  1e-5f
#define NT1B  157             // 128-row tiles (fused1)
#define MOUT  104             // out-tile nodes per fused2 block
#define NT2B  193             // ceil(20000/104)

#define XRS   272             // xr/t4 row stride (17x16B -> conflict-free)

typedef __bf16  bf16x8 __attribute__((ext_vector_type(8)));
typedef float   f32x4  __attribute__((ext_vector_type(4)));
typedef ushort  u16x8  __attribute__((ext_vector_type(8)));

__device__ __forceinline__ float sigmoidf_(float x) { return 1.0f / (1.0f + expf(-x)); }

__device__ __forceinline__ ushort f2bf(float f) {
    __hip_bfloat16 h = __float2bfloat16(f);
    return __builtin_bit_cast(ushort, h);
}
__device__ __forceinline__ float bf2f(ushort u) {
    return __builtin_bit_cast(float, ((unsigned int)u) << 16);
}
__device__ __forceinline__ int wrapN(int v) {
    return (v < 0) ? v + NN : ((v >= NN) ? v - NN : v);
}

#define LDSP(p) ((__attribute__((address_space(3))) unsigned int*)(p))
#define GBLP(p) ((const __attribute__((address_space(1))) unsigned int*)(p))
#define GLD16(g, l) __builtin_amdgcn_global_load_lds(GBLP(g), LDSP(l), 16, 0, 0)

// bnrelu from bf16 global chunk -> two f32x4
__device__ __forceinline__ void bnrelu_f32(const u16x8 a, const float* ssS, int fb,
                                           f32x4& o0, f32x4& o1) {
    const f32x4 sc0 = *reinterpret_cast<const f32x4*>(ssS + fb);
    const f32x4 sc1 = *reinterpret_cast<const f32x4*>(ssS + fb + 4);
    const f32x4 sh0 = *reinterpret_cast<const f32x4*>(ssS + 256 + fb);
    const f32x4 sh1 = *reinterpret_cast<const f32x4*>(ssS + 256 + fb + 4);
    #pragma unroll
    for (int j = 0; j < 4; ++j) {
        o0[j] = fmaxf(bf2f(a[j])     * sc0[j] + sh0[j], 0.f);
        o1[j] = fmaxf(bf2f(a[4 + j]) * sc1[j] + sh1[j], 0.f);
    }
}

// pass1: T4[r4] = sum of 4 consecutive f32 xr rows -> f32 LDS (v_pk_add_f32)
__device__ __forceinline__ void t4_item(const char* xr, char* t4, int r4, int c8) {
    f32x4 s0 = {}, s1 = {};
    #pragma unroll
    for (int j = 0; j < 4; ++j) {
        s0 += *reinterpret_cast<const f32x4*>(xr + (r4 + j) * XRS + c8 * 32);
        s1 += *reinterpret_cast<const f32x4*>(xr + (r4 + j) * XRS + c8 * 32 + 16);
    }
    *reinterpret_cast<f32x4*>(t4 + r4 * XRS + c8 * 32)      = s0;
    *reinterpret_cast<f32x4*>(t4 + r4 * XRS + c8 * 32 + 16) = s1;
}

// pass2: As[row] = (T4[row]+T4[row+4]+T4[row+8]+T4[row+12]+xr[row+16])/17 -> bf16 swizzled
__device__ __forceinline__ void as_item(const char* xr, const char* t4, char* As,
                                        int row, int c8, float inv17) {
    f32x4 s0 = *reinterpret_cast<const f32x4*>(t4 + row * XRS + c8 * 32);
    f32x4 s1 = *reinterpret_cast<const f32x4*>(t4 + row * XRS + c8 * 32 + 16);
    #pragma unroll
    for (int m = 4; m <= 12; m += 4) {
        s0 += *reinterpret_cast<const f32x4*>(t4 + (row + m) * XRS + c8 * 32);
        s1 += *reinterpret_cast<const f32x4*>(t4 + (row + m) * XRS + c8 * 32 + 16);
    }
    s0 += *reinterpret_cast<const f32x4*>(xr + (row + 16) * XRS + c8 * 32);
    s1 += *reinterpret_cast<const f32x4*>(xr + (row + 16) * XRS + c8 * 32 + 16);
    u16x8 o;
    #pragma unroll
    for (int j = 0; j < 4; ++j) o[j]     = f2bf(s0[j] * inv17);
    #pragma unroll
    for (int j = 0; j < 4; ++j) o[4 + j] = f2bf(s1[j] * inv17);
    *reinterpret_cast<u16x8*>(As + row * 128 + ((c8 ^ (row & 7)) * 16)) = o;
}

// ============ kernel 1: prep (W1t, W2t, zero asum), 49 blocks ============
__global__ __launch_bounds__(512, 2) void k_prep(const float* __restrict__ W1,
    const float* __restrict__ W2, ushort* __restrict__ W1t,
    ushort* __restrict__ W2t, float* __restrict__ asum)
{
    const int b = blockIdx.x, t = threadIdx.x;
    if (b < 16) {
        const int e = (b * 512 + t) * 4;            // W1t: 32768 elements
        ushort4 o;
        #pragma unroll
        for (int j = 0; j < 4; ++j) {
            const int ee = e + j;
            const int n = ee >> 7, k = ee & 127;    // W1t[n][k] = W1[k][n]
            ((ushort*)&o)[j] = f2bf(W1[k * 256 + n]);
        }
        *reinterpret_cast<ushort4*>(W1t + e) = o;
    } else if (b < 48) {
        const int e = ((b - 16) * 512 + t) * 4;     // W2t: 65536 elements
        ushort4 o;
        #pragma unroll
        for (int j = 0; j < 4; ++j) {
            const int ee = e + j;
            const int n = ee >> 8, k = ee & 255;    // W2t[n][k] = W2[k][n]
            ((ushort*)&o)[j] = f2bf(W2[k * 256 + n]);
        }
        *reinterpret_cast<ushort4*>(W2t + e) = o;
    } else {
        asum[t]       = 0.f;
        asum[512 + t] = 0.f;
    }
}

// ====== kernel 2: A = agg(x) @ W1 + b1; BN partials -> asum. 157 blocks x 1024 ======
// xr/t4 in f32 (272B rows); two-level agg; T14 prefetch; T5 setprio.
__global__ __launch_bounds__(1024, 4) void k_fused1(const float* __restrict__ x,
    const ushort* __restrict__ W1t, const float* __restrict__ b1,
    ushort* __restrict__ A, float* __restrict__ asum)
{
    __shared__ alignas(16) char smem[39168 + 39168 + 16384 + 32768];
    char* xr = smem;                             // 144 x 272B (f32)
    char* t4 = smem + 39168;                     // 144 x 272B (f32 T4 sums)
    char* As = smem + 39168 + 39168;             // 128 x 128B (bf16, swizzled)
    char* Bs = smem + 39168 + 39168 + 16384;     // 256 x 128B (bf16, swizzled)

    const int t = threadIdx.x;
    const int wave = t >> 6, lane = t & 63;
    const int wr  = (wave >> 2) * 32;   // 4 row-quads
    const int wc4 = (wave & 3) * 64;    // 4 col groups of 64
    const int bm = blockIdx.x * 128;
    const float inv17 = 1.0f / 17.0f;
    f32x4 acc[2][4] = {};               // [mi][ni]

    const int rw0 = wrapN(bm - 8 + (t >> 3)),          c80 = (t & 7) * 8;
    const int rw1 = wrapN(bm - 8 + ((1024 + t) >> 3)), c81 = ((1024 + t) & 7) * 8;
    const bool v1 = t < 128;

    float4 xa0 = *reinterpret_cast<const float4*>(x + (size_t)rw0 * INFEAT + c80);
    float4 xa1 = *reinterpret_cast<const float4*>(x + (size_t)rw0 * INFEAT + c80 + 4);
    float4 xb0 = v1 ? *reinterpret_cast<const float4*>(x + (size_t)rw1 * INFEAT + c81)
                    : make_float4(0.f, 0.f, 0.f, 0.f);
    float4 xb1 = v1 ? *reinterpret_cast<const float4*>(x + (size_t)rw1 * INFEAT + c81 + 4)
                    : make_float4(0.f, 0.f, 0.f, 0.f);

    #pragma unroll
    for (int kt = 0; kt < 2; ++kt) {
        const int k0 = kt * 64;
        {   // write staged x -> xr (f32, no conversion)
            const int r0 = t >> 3, c8 = t & 7;
            *reinterpret_cast<float4*>(xr + r0 * XRS + c8 * 32)      = xa0;
            *reinterpret_cast<float4*>(xr + r0 * XRS + c8 * 32 + 16) = xa1;
            if (v1) {
                const int r1 = (1024 + t) >> 3, c81l = (1024 + t) & 7;
                *reinterpret_cast<float4*>(xr + r1 * XRS + c81l * 32)      = xb0;
                *reinterpret_cast<float4*>(xr + r1 * XRS + c81l * 32 + 16) = xb1;
            }
        }
        __syncthreads();   // sync A: xr ready; MFMA(kt-1) done
        #pragma unroll
        for (int it = 0; it < 2; ++it) {   // stage B(kt): 2048 chunks
            const int cb = (it * 16 + wave) * 64 + lane;
            const int row = cb >> 3;
            const int lk = (cb & 7) ^ (row & 7);
            GLD16(W1t + (size_t)row * INFEAT + k0 + lk * 8, Bs + (it * 16 + wave) * 1024);
        }
        // pass1: T4 sums
        t4_item(xr, t4, t >> 3, t & 7);
        if (v1) t4_item(xr, t4, 128 + (t >> 3), t & 7);
        __syncthreads();   // sync C: t4 ready (B DMA drains here)
        // pass2: As via 5-tap combine
        as_item(xr, t4, As, t >> 3, t & 7, inv17);
        __syncthreads();   // sync B: As + Bs ready
        if (kt == 0) {
            xa0 = *reinterpret_cast<const float4*>(x + (size_t)rw0 * INFEAT + 64 + c80);
            xa1 = *reinterpret_cast<const float4*>(x + (size_t)rw0 * INFEAT + 64 + c80 + 4);
            if (v1) {
                xb0 = *reinterpret_cast<const float4*>(x + (size_t)rw1 * INFEAT + 64 + c81);
                xb1 = *reinterpret_cast<const float4*>(x + (size_t)rw1 * INFEAT + 64 + c81 + 4);
            }
        }
        __builtin_amdgcn_s_setprio(1);
        #pragma unroll
        for (int kk = 0; kk < 2; ++kk) {
            const int klog = kk * 64 + ((lane >> 4) << 4);
            bf16x8 af[2];
            #pragma unroll
            for (int mi = 0; mi < 2; ++mi) {
                const int row = wr + mi * 16 + (lane & 15);
                af[mi] = *reinterpret_cast<const bf16x8*>(As + row * 128 + (klog ^ ((row & 7) << 4)));
            }
            #pragma unroll
            for (int ni = 0; ni < 4; ++ni) {
                const int rl = wc4 + ni * 16 + (lane & 15);
                const bf16x8 bv = *reinterpret_cast<const bf16x8*>(Bs + rl * 128 + (klog ^ ((rl & 7) << 4)));
                #pragma unroll
                for (int mi = 0; mi < 2; ++mi)
                    acc[mi][ni] = __builtin_amdgcn_mfma_f32_16x16x32_bf16(af[mi], bv, acc[mi][ni], 0, 0, 0);
            }
        }
        __builtin_amdgcn_s_setprio(0);
        // no trailing barrier: next-kt xr/t4 writes disjoint from As/Bs; B-GLD16 behind next sync
    }

    // epilogue: bias, store A (bf16), BN partials -> asum (atomic)
    float* sS  = (float*)smem;            // [16][64]
    float* s2S = (float*)(smem + 4096);   // [16][64]
    #pragma unroll
    for (int ni = 0; ni < 4; ++ni) {
        const int colL = wc4 + ni * 16 + (lane & 15);
        const float bv = b1[colL];
        float sv = 0.f, s2v = 0.f;
        #pragma unroll
        for (int mi = 0; mi < 2; ++mi)
            #pragma unroll
            for (int r = 0; r < 4; ++r) {
                const int row = bm + wr + mi * 16 + ((lane >> 4) << 2) + r;
                if (row < NN) {
                    const float val = acc[mi][ni][r] + bv;
                    A[(size_t)row * 256 + colL] = f2bf(val);
                    sv += val; s2v += val * val;
                }
            }
        sv  += __shfl_xor(sv, 16);  sv  += __shfl_xor(sv, 32);
        s2v += __shfl_xor(s2v, 16); s2v += __shfl_xor(s2v, 32);
        if (lane < 16) {
            sS [wave * 64 + ni * 16 + lane] = sv;
            s2S[wave * 64 + ni * 16 + lane] = s2v;
        }
    }
    __syncthreads();
    if (t < 256) {
        const int col = t;
        const int g = col >> 6, idx = col & 63;
        float s = 0.f, s2 = 0.f;
        #pragma unroll
        for (int wv = g; wv < 16; wv += 4) {
            s  += sS [wv * 64 + idx];
            s2 += s2S[wv * 64 + idx];
        }
        atomicAdd(&asum[col],       s);
        atomicAdd(&asum[512 + col], s2);
    }
}

// ===== kernel 3: h2 = relu( agg(relu(bn(A))) @ W2 + b2 ), dots, P, edge outputs =====
// Out-tile M=104; GEMM rows 128 (halo recompute). f32 xr/t4; two-level agg.
__global__ __launch_bounds__(1024, 4) void k_fused2(const ushort* __restrict__ A,
    const ushort* __restrict__ W2t, const float* __restrict__ gamma,
    const float* __restrict__ beta, const float* __restrict__ b2,
    const float* __restrict__ Wl, const float* __restrict__ bl,
    const float* __restrict__ asum, float* __restrict__ out)
{
    __shared__ alignas(16) char smem[39168 + 39168 + 16384 + 32768 + 2048];
    char* xr   = smem;                               // 144 x 272B (f32 bnrelu'd)
    char* t4   = smem + 39168;                       // 144 x 272B (f32 T4 sums)
    char* As   = smem + 39168 + 39168;               // 128 x 128B swizzled
    char* Bs   = smem + 39168 + 39168 + 16384;       // 256 x 128B swizzled
    float* ssS = (float*)(smem + 39168 + 39168 + 16384 + 32768);  // sc|sh

    const int b = blockIdx.x, t = threadIdx.x;
    const int wave = t >> 6, lane = t & 63;
    const int wr  = (wave >> 2) * 32;       // 4 row-quads
    const int wc4 = (wave & 3) * 64;        // 4 col groups of 64
    const int v0 = b * MOUT;
    const float inv17 = 1.0f / 17.0f;

    if (t < 256) {
        const float invn = 1.0f / (float)NN;
        const float mu  = asum[t] * invn;
        const float var = asum[512 + t] * invn - mu * mu;
        const float sc  = gamma[t] * rsqrtf(var + EPSF);
        ssS[t]       = sc;
        ssS[256 + t] = beta[t] - mu * sc;
    }
    __syncthreads();

    f32x4 acc[2][4] = {};   // [mi][ni]

    const int rg0 = wrapN(v0 - 16 + (t >> 3)),          f80 = (t & 7) * 8;
    const int rg1 = wrapN(v0 - 16 + ((1024 + t) >> 3)), f81 = ((1024 + t) & 7) * 8;
    const bool v1 = t < 128;

    u16x8 aq0 = *reinterpret_cast<const u16x8*>(A + (size_t)rg0 * 256 + f80);
    u16x8 aq1 = v1 ? *reinterpret_cast<const u16x8*>(A + (size_t)rg1 * 256 + f81)
                   : u16x8{};

    #pragma unroll
    for (int kt = 0; kt < 4; ++kt) {
        const int k0 = kt * 64;
        {   // bnrelu + write staged A -> xr (f32)
            f32x4 o0, o1;
            bnrelu_f32(aq0, ssS, k0 + f80, o0, o1);
            const int r0 = t >> 3, c8 = t & 7;
            *reinterpret_cast<f32x4*>(xr + r0 * XRS + c8 * 32)      = o0;
            *reinterpret_cast<f32x4*>(xr + r0 * XRS + c8 * 32 + 16) = o1;
            if (v1) {
                bnrelu_f32(aq1, ssS, k0 + f81, o0, o1);
                const int r1 = (1024 + t) >> 3, c81l = (1024 + t) & 7;
                *reinterpret_cast<f32x4*>(xr + r1 * XRS + c81l * 32)      = o0;
                *reinterpret_cast<f32x4*>(xr + r1 * XRS + c81l * 32 + 16) = o1;
            }
        }
        __syncthreads();   // sync A
        #pragma unroll
        for (int it = 0; it < 2; ++it) {   // stage B(kt): 2048 chunks
            const int cb = (it * 16 + wave) * 64 + lane;
            const int row = cb >> 3;
            const int lk = (cb & 7) ^ (row & 7);
            GLD16(W2t + (size_t)row * 256 + k0 + lk * 8, Bs + (it * 16 + wave) * 1024);
        }
        // pass1: T4 sums
        t4_item(xr, t4, t >> 3, t & 7);
        if (v1) t4_item(xr, t4, 128 + (t >> 3), t & 7);
        __syncthreads();   // sync C
        // pass2: As via 5-tap combine
        as_item(xr, t4, As, t >> 3, t & 7, inv17);
        __syncthreads();   // sync B
        if (kt < 3) {
            const int k1 = k0 + 64;
            aq0 = *reinterpret_cast<const u16x8*>(A + (size_t)rg0 * 256 + k1 + f80);
            if (v1)
                aq1 = *reinterpret_cast<const u16x8*>(A + (size_t)rg1 * 256 + k1 + f81);
        }
        __builtin_amdgcn_s_setprio(1);
        #pragma unroll
        for (int kk = 0; kk < 2; ++kk) {
            const int klog = kk * 64 + ((lane >> 4) << 4);
            bf16x8 af[2];
            #pragma unroll
            for (int mi = 0; mi < 2; ++mi) {
                const int row = wr + mi * 16 + (lane & 15);
                af[mi] = *reinterpret_cast<const bf16x8*>(As + row * 128 + (klog ^ ((row & 7) << 4)));
            }
            #pragma unroll
            for (int ni = 0; ni < 4; ++ni) {
                const int rl = wc4 + ni * 16 + (lane & 15);
                const bf16x8 bv = *reinterpret_cast<const bf16x8*>(Bs + rl * 128 + (klog ^ ((rl & 7) << 4)));
                #pragma unroll
                for (int mi = 0; mi < 2; ++mi)
                    acc[mi][ni] = __builtin_amdgcn_mfma_f32_16x16x32_bf16(af[mi], bv, acc[mi][ni], 0, 0, 0);
            }
        }
        __builtin_amdgcn_s_setprio(0);
        // no trailing barrier
    }

    // epilogue: relu + per-row partial dots over this wave's 64 cols -> uW/wW
    float b2v[4], wav[4], wbv[4];
    #pragma unroll
    for (int ni = 0; ni < 4; ++ni) {
        const int col = wc4 + ni * 16 + (lane & 15);
        b2v[ni] = b2[col];
        wav[ni] = Wl[col];
        wbv[ni] = Wl[256 + col];
    }
    float* uW = (float*)smem;            // [4 col-groups][128 rows]
    float* wW = (float*)(smem + 2048);   // [4][128]
    float* uL = (float*)(smem + 23040);         // [128]
    float* wL = (float*)(smem + 23040 + 512);   // [128]
    float* PS = (float*)(smem + 23040 + 1024);  // [112]
    #pragma unroll
    for (int mi = 0; mi < 2; ++mi)
        #pragma unroll
        for (int r = 0; r < 4; ++r) {
            float pu = 0.f, pw = 0.f;
            #pragma unroll
            for (int ni = 0; ni < 4; ++ni) {
                const float hv = fmaxf(acc[mi][ni][r] + b2v[ni], 0.f);
                pu += hv * wav[ni];
                pw += hv * wbv[ni];
            }
            pu += __shfl_xor(pu, 1); pu += __shfl_xor(pu, 2);
            pu += __shfl_xor(pu, 4); pu += __shfl_xor(pu, 8);
            pw += __shfl_xor(pw, 1); pw += __shfl_xor(pw, 2);
            pw += __shfl_xor(pw, 4); pw += __shfl_xor(pw, 8);
            if ((lane & 15) == 0) {
                const int rl = wr + mi * 16 + ((lane >> 4) << 2) + r;
                uW[(wave & 3) * 128 + rl] = pu;
                wW[(wave & 3) * 128 + rl] = pw;
            }
        }
    __syncthreads();
    if (t < 128) {
        uL[t] = uW[t] + uW[128 + t] + uW[256 + t] + uW[384 + t];
        wL[t] = wW[t] + wW[128 + t] + wW[256 + t] + wW[384 + t];
    }
    __syncthreads();

    // P for nodes [v0, v0+112): PS[i] uses uL[i..i+16], wL[i+8]
    if (t < 112) {
        const int l = t + 8;
        float s = uL[l] + 16.0f * wL[l];
        #pragma unroll
        for (int o = 1; o <= 8; ++o)
            s += uL[l + o] + uL[l - o];
        PS[t] = s;
    }
    __syncthreads();

    // edge outputs for nodes [v0, v0+104)
    const float blv = bl[0];
    #pragma unroll
    for (int rr = 0; rr < 2; ++rr) {
        const int q = t + rr * 1024;             // [0, 2048); valid < 1664
        if (q >= 1664) continue;
        const int half = (q >= 832) ? 1 : 0;
        const int e = q - half * 832;
        const int i = e >> 3, off = e & 7;
        const int v = v0 + i;
        if (v >= NN) continue;
        if (!half) {   // forward edge (v -> v+1+off): P[v] + w[v+1+off]
            out[v * 8 + off] = sigmoidf_((PS[i] + wL[i + 9 + off]) * inv17 + blv);
        } else {       // reverse edge owned by tt = v: P[v+1+off] + w[v]
            out[NK + v * 8 + off] = sigmoidf_((PS[i + 1 + off] + wL[i + 8]) * inv17 + blv);
        }
    }
}

// ---------------- launch ----------------
extern "C" void kernel_launch(void* const* d_in, const int* in_sizes, int n_in,
                              void* d_out, int out_size, void* d_ws, size_t ws_size,
                              hipStream_t stream)
{
    const float* x      = (const float*)d_in[0];
    const float* W1     = (const float*)d_in[1];
    const float* b1     = (const float*)d_in[2];
    const float* gamma1 = (const float*)d_in[3];
    const float* beta1  = (const float*)d_in[4];
    const float* W2     = (const float*)d_in[5];
    const float* b2     = (const float*)d_in[6];
    const float* Wl     = (const float*)d_in[7];
    const float* bl     = (const float*)d_in[8];
    float* out = (float*)d_out;

    float*    asum = (float*)d_ws;                   // [1024]
    ushort*   A    = (ushort*)(asum + 1024);         // [NN,256] bf16
    ushort*   W1t  = A + (size_t)NN * 256;           // [256,128]
    ushort*   W2t  = W1t + 256 * 128;                // [256,256]

    k_prep  <<<49,   512,  0, stream>>>(W1, W2, W1t, W2t, asum);
    k_fused1<<<NT1B, 1024, 0, stream>>>(x, W1t, b1, A, asum);
    k_fused2<<<NT2B, 1024, 0, stream>>>(A, W2t, gamma1, beta1, b2, Wl, bl, asum, out);
}

// Round 24
// 41.504 us; speedup vs baseline: 1.0263x; 1.0263x over previous
//
#include <hip/hip_runtime.h>
#include <hip/hip_bf16.h>
#include <math.h>

#define NN    20000
#define NK    160000          // NN*8
#define NEDGE 320000
#define HID   256
#define INFEAT 128
#define EPSF  1e-5f
#define NT1B  157             // 128-row tiles (fused1)
#define MOUT  104             // out-tile nodes per fused2 block
#define NT2B  193             // ceil(20000/104)

#define T4S   272             // t4 row stride in bytes (17x16B -> conflict-free)

typedef __bf16  bf16x8 __attribute__((ext_vector_type(8)));
typedef float   f32x4  __attribute__((ext_vector_type(4)));
typedef ushort  u16x8  __attribute__((ext_vector_type(8)));

__device__ __forceinline__ float sigmoidf_(float x) { return 1.0f / (1.0f + expf(-x)); }

__device__ __forceinline__ ushort f2bf(float f) {
    __hip_bfloat16 h = __float2bfloat16(f);
    return __builtin_bit_cast(ushort, h);
}
__device__ __forceinline__ float bf2f(ushort u) {
    return __builtin_bit_cast(float, ((unsigned int)u) << 16);
}
__device__ __forceinline__ int wrapN(int v) {
    return (v < 0) ? v + NN : ((v >= NN) ? v - NN : v);
}

#define LDSP(p) ((__attribute__((address_space(3))) unsigned int*)(p))
#define GBLP(p) ((const __attribute__((address_space(1))) unsigned int*)(p))
#define GLD16(g, l) __builtin_amdgcn_global_load_lds(GBLP(g), LDSP(l), 16, 0, 0)

__device__ __forceinline__ u16x8 bnrelu8(const u16x8 a, const float* ssS, int fb) {
    const float4 sc0 = *reinterpret_cast<const float4*>(ssS + fb);
    const float4 sc1 = *reinterpret_cast<const float4*>(ssS + fb + 4);
    const float4 sh0 = *reinterpret_cast<const float4*>(ssS + 256 + fb);
    const float4 sh1 = *reinterpret_cast<const float4*>(ssS + 256 + fb + 4);
    u16x8 p;
    p[0] = f2bf(fmaxf(bf2f(a[0]) * sc0.x + sh0.x, 0.f));
    p[1] = f2bf(fmaxf(bf2f(a[1]) * sc0.y + sh0.y, 0.f));
    p[2] = f2bf(fmaxf(bf2f(a[2]) * sc0.z + sh0.z, 0.f));
    p[3] = f2bf(fmaxf(bf2f(a[3]) * sc0.w + sh0.w, 0.f));
    p[4] = f2bf(fmaxf(bf2f(a[4]) * sc1.x + sh1.x, 0.f));
    p[5] = f2bf(fmaxf(bf2f(a[5]) * sc1.y + sh1.y, 0.f));
    p[6] = f2bf(fmaxf(bf2f(a[6]) * sc1.z + sh1.z, 0.f));
    p[7] = f2bf(fmaxf(bf2f(a[7]) * sc1.w + sh1.w, 0.f));
    return p;
}

__device__ __forceinline__ u16x8 pack8(const float4 a, const float4 b) {
    u16x8 p;
    p[0] = f2bf(a.x); p[1] = f2bf(a.y); p[2] = f2bf(a.z); p[3] = f2bf(a.w);
    p[4] = f2bf(b.x); p[5] = f2bf(b.y); p[6] = f2bf(b.z); p[7] = f2bf(b.w);
    return p;
}

// pass1 helper: T4[r4] = sum of 4 consecutive bf16 xr rows -> f32 LDS (272B stride)
__device__ __forceinline__ void t4_item(const char* xr, char* t4, int r4, int c8) {
    float S[8] = {};
    #pragma unroll
    for (int j = 0; j < 4; ++j) {
        const u16x8 h = *reinterpret_cast<const u16x8*>(xr + (r4 + j) * 160 + c8 * 16);
        #pragma unroll
        for (int e = 0; e < 8; ++e) S[e] += bf2f(h[e]);
    }
    *reinterpret_cast<float4*>(t4 + r4 * T4S + c8 * 32)
        = make_float4(S[0], S[1], S[2], S[3]);
    *reinterpret_cast<float4*>(t4 + r4 * T4S + c8 * 32 + 16)
        = make_float4(S[4], S[5], S[6], S[7]);
}

// pass2 helper: As[row] = (T4[row]+T4[row+4]+T4[row+8]+T4[row+12]+xr[row+16])/17
__device__ __forceinline__ void as_item(const char* xr, const char* t4, char* As,
                                        int row, int c8, float inv17) {
    float S[8];
    const float4 a0 = *reinterpret_cast<const float4*>(t4 + row * T4S + c8 * 32);
    const float4 a1 = *reinterpret_cast<const float4*>(t4 + row * T4S + c8 * 32 + 16);
    const float4 b0 = *reinterpret_cast<const float4*>(t4 + (row + 4) * T4S + c8 * 32);
    const float4 b1 = *reinterpret_cast<const float4*>(t4 + (row + 4) * T4S + c8 * 32 + 16);
    const float4 c0 = *reinterpret_cast<const float4*>(t4 + (row + 8) * T4S + c8 * 32);
    const float4 c1 = *reinterpret_cast<const float4*>(t4 + (row + 8) * T4S + c8 * 32 + 16);
    const float4 d0 = *reinterpret_cast<const float4*>(t4 + (row + 12) * T4S + c8 * 32);
    const float4 d1 = *reinterpret_cast<const float4*>(t4 + (row + 12) * T4S + c8 * 32 + 16);
    const u16x8 hx = *reinterpret_cast<const u16x8*>(xr + (row + 16) * 160 + c8 * 16);
    S[0] = a0.x + b0.x + c0.x + d0.x + bf2f(hx[0]);
    S[1] = a0.y + b0.y + c0.y + d0.y + bf2f(hx[1]);
    S[2] = a0.z + b0.z + c0.z + d0.z + bf2f(hx[2]);
    S[3] = a0.w + b0.w + c0.w + d0.w + bf2f(hx[3]);
    S[4] = a1.x + b1.x + c1.x + d1.x + bf2f(hx[4]);
    S[5] = a1.y + b1.y + c1.y + d1.y + bf2f(hx[5]);
    S[6] = a1.z + b1.z + c1.z + d1.z + bf2f(hx[6]);
    S[7] = a1.w + b1.w + c1.w + d1.w + bf2f(hx[7]);
    u16x8 o;
    #pragma unroll
    for (int j = 0; j < 8; ++j) o[j] = f2bf(S[j] * inv17);
    *reinterpret_cast<u16x8*>(As + row * 128 + ((c8 ^ (row & 7)) * 16)) = o;
}

// ============ kernel 1: prep (W1t, W2t, zero asum), 49 blocks ============
__global__ __launch_bounds__(512, 2) void k_prep(const float* __restrict__ W1,
    const float* __restrict__ W2, ushort* __restrict__ W1t,
    ushort* __restrict__ W2t, float* __restrict__ asum)
{
    const int b = blockIdx.x, t = threadIdx.x;
    if (b < 16) {
        const int e = (b * 512 + t) * 4;            // W1t: 32768 elements
        ushort4 o;
        #pragma unroll
        for (int j = 0; j < 4; ++j) {
            const int ee = e + j;
            const int n = ee >> 7, k = ee & 127;    // W1t[n][k] = W1[k][n]
            ((ushort*)&o)[j] = f2bf(W1[k * 256 + n]);
        }
        *reinterpret_cast<ushort4*>(W1t + e) = o;
    } else if (b < 48) {
        const int e = ((b - 16) * 512 + t) * 4;     // W2t: 65536 elements
        ushort4 o;
        #pragma unroll
        for (int j = 0; j < 4; ++j) {
            const int ee = e + j;
            const int n = ee >> 8, k = ee & 255;    // W2t[n][k] = W2[k][n]
            ((ushort*)&o)[j] = f2bf(W2[k * 256 + n]);
        }
        *reinterpret_cast<ushort4*>(W2t + e) = o;
    } else {
        asum[t]       = 0.f;
        asum[512 + t] = 0.f;
    }
}

// ====== kernel 2: A = agg(x) @ W1 + b1; BN partials -> asum. 157 blocks x 1024 ======
// Two-level agg (bf16 xr, padded t4). T14 prefetch; T5 setprio.
__global__ __launch_bounds__(1024, 4) void k_fused1(const float* __restrict__ x,
    const ushort* __restrict__ W1t, const float* __restrict__ b1,
    ushort* __restrict__ A, float* __restrict__ asum)
{
    __shared__ alignas(16) char smem[23040 + 39168 + 16384 + 32768];
    char* xr = smem;                             // 144 x 160B (bf16, padded)
    char* t4 = smem + 23040;                     // 144 x 272B (f32 T4 sums)
    char* As = smem + 23040 + 39168;             // 128 x 128B (bf16, swizzled)
    char* Bs = smem + 23040 + 39168 + 16384;     // 256 x 128B (bf16, swizzled)

    const int t = threadIdx.x;
    const int wave = t >> 6, lane = t & 63;
    const int wr  = (wave >> 2) * 32;   // 4 row-quads
    const int wc4 = (wave & 3) * 64;    // 4 col groups of 64
    const int bm = blockIdx.x * 128;
    const float inv17 = 1.0f / 17.0f;
    f32x4 acc[2][4] = {};               // [mi][ni]

    const int rw0 = wrapN(bm - 8 + (t >> 3)),          c80 = (t & 7) * 8;
    const int rw1 = wrapN(bm - 8 + ((1024 + t) >> 3)), c81 = ((1024 + t) & 7) * 8;
    const bool v1 = t < 128;

    float4 xa0 = *reinterpret_cast<const float4*>(x + (size_t)rw0 * INFEAT + c80);
    float4 xa1 = *reinterpret_cast<const float4*>(x + (size_t)rw0 * INFEAT + c80 + 4);
    float4 xb0 = v1 ? *reinterpret_cast<const float4*>(x + (size_t)rw1 * INFEAT + c81)
                    : make_float4(0.f, 0.f, 0.f, 0.f);
    float4 xb1 = v1 ? *reinterpret_cast<const float4*>(x + (size_t)rw1 * INFEAT + c81 + 4)
                    : make_float4(0.f, 0.f, 0.f, 0.f);

    #pragma unroll
    for (int kt = 0; kt < 2; ++kt) {
        const int k0 = kt * 64;
        *reinterpret_cast<u16x8*>(xr + (t >> 3) * 160 + (t & 7) * 16) = pack8(xa0, xa1);
        if (v1)
            *reinterpret_cast<u16x8*>(xr + ((1024 + t) >> 3) * 160 + ((1024 + t) & 7) * 16) = pack8(xb0, xb1);
        __syncthreads();   // sync A: xr ready; MFMA(kt-1) done
        #pragma unroll
        for (int it = 0; it < 2; ++it) {   // stage B(kt): 2048 chunks
            const int cb = (it * 16 + wave) * 64 + lane;
            const int row = cb >> 3;
            const int lk = (cb & 7) ^ (row & 7);
            GLD16(W1t + (size_t)row * INFEAT + k0 + lk * 8, Bs + (it * 16 + wave) * 1024);
        }
        // pass1: T4 sums (1128 items)
        t4_item(xr, t4, t >> 3, t & 7);
        if (v1) t4_item(xr, t4, 128 + (t >> 3), t & 7);
        __syncthreads();   // sync C: t4 ready (B DMA drains here)
        // pass2: As[row] via 5-tap combine
        as_item(xr, t4, As, t >> 3, t & 7, inv17);
        __syncthreads();   // sync B: As + Bs ready
        if (kt == 0) {
            xa0 = *reinterpret_cast<const float4*>(x + (size_t)rw0 * INFEAT + 64 + c80);
            xa1 = *reinterpret_cast<const float4*>(x + (size_t)rw0 * INFEAT + 64 + c80 + 4);
            if (v1) {
                xb0 = *reinterpret_cast<const float4*>(x + (size_t)rw1 * INFEAT + 64 + c81);
                xb1 = *reinterpret_cast<const float4*>(x + (size_t)rw1 * INFEAT + 64 + c81 + 4);
            }
        }
        __builtin_amdgcn_s_setprio(1);
        #pragma unroll
        for (int kk = 0; kk < 2; ++kk) {
            const int klog = kk * 64 + ((lane >> 4) << 4);
            bf16x8 af[2];
            #pragma unroll
            for (int mi = 0; mi < 2; ++mi) {
                const int row = wr + mi * 16 + (lane & 15);
                af[mi] = *reinterpret_cast<const bf16x8*>(As + row * 128 + (klog ^ ((row & 7) << 4)));
            }
            #pragma unroll
            for (int ni = 0; ni < 4; ++ni) {
                const int rl = wc4 + ni * 16 + (lane & 15);
                const bf16x8 bv = *reinterpret_cast<const bf16x8*>(Bs + rl * 128 + (klog ^ ((rl & 7) << 4)));
                #pragma unroll
                for (int mi = 0; mi < 2; ++mi)
                    acc[mi][ni] = __builtin_amdgcn_mfma_f32_16x16x32_bf16(af[mi], bv, acc[mi][ni], 0, 0, 0);
            }
        }
        __builtin_amdgcn_s_setprio(0);
        // no trailing barrier: next-kt xr/t4 writes disjoint from As/Bs; B-GLD16 behind next sync
    }

    // epilogue: bias, store A (bf16), BN partials -> asum (atomic)
    float* sS  = (float*)smem;            // [16][64]
    float* s2S = (float*)(smem + 4096);   // [16][64]
    #pragma unroll
    for (int ni = 0; ni < 4; ++ni) {
        const int colL = wc4 + ni * 16 + (lane & 15);
        const float bv = b1[colL];
        float sv = 0.f, s2v = 0.f;
        #pragma unroll
        for (int mi = 0; mi < 2; ++mi)
            #pragma unroll
            for (int r = 0; r < 4; ++r) {
                const int row = bm + wr + mi * 16 + ((lane >> 4) << 2) + r;
                if (row < NN) {
                    const float val = acc[mi][ni][r] + bv;
                    A[(size_t)row * 256 + colL] = f2bf(val);
                    sv += val; s2v += val * val;
                }
            }
        sv  += __shfl_xor(sv, 16);  sv  += __shfl_xor(sv, 32);
        s2v += __shfl_xor(s2v, 16); s2v += __shfl_xor(s2v, 32);
        if (lane < 16) {
            sS [wave * 64 + ni * 16 + lane] = sv;
            s2S[wave * 64 + ni * 16 + lane] = s2v;
        }
    }
    __syncthreads();
    if (t < 256) {
        const int col = t;
        const int g = col >> 6, idx = col & 63;
        float s = 0.f, s2 = 0.f;
        #pragma unroll
        for (int wv = g; wv < 16; wv += 4) {
            s  += sS [wv * 64 + idx];
            s2 += s2S[wv * 64 + idx];
        }
        atomicAdd(&asum[col],       s);
        atomicAdd(&asum[512 + col], s2);
    }
}

// ===== kernel 3: h2 = relu( agg(relu(bn(A))) @ W2 + b2 ), dots, P, edge outputs =====
// Out-tile M=104; GEMM rows 128 (halo recompute). 193 blocks x 1024. Two-level agg.
__global__ __launch_bounds__(1024, 4) void k_fused2(const ushort* __restrict__ A,
    const ushort* __restrict__ W2t, const float* __restrict__ gamma,
    const float* __restrict__ beta, const float* __restrict__ b2,
    const float* __restrict__ Wl, const float* __restrict__ bl,
    const float* __restrict__ asum, float* __restrict__ out)
{
    __shared__ alignas(16) char smem[23040 + 39168 + 16384 + 32768 + 2048];
    char* xr   = smem;                              // 144 x 160B (bf16 bnrelu'd)
    char* t4   = smem + 23040;                      // 144 x 272B (f32 T4 sums)
    char* As   = smem + 23040 + 39168;              // 128 x 128B swizzled
    char* Bs   = smem + 23040 + 39168 + 16384;      // 256 x 128B swizzled
    float* ssS = (float*)(smem + 23040 + 39168 + 16384 + 32768);  // sc|sh

    const int b = blockIdx.x, t = threadIdx.x;
    const int wave = t >> 6, lane = t & 63;
    const int wr  = (wave >> 2) * 32;       // 4 row-quads
    const int wc4 = (wave & 3) * 64;        // 4 col groups of 64
    const int v0 = b * MOUT;
    const float inv17 = 1.0f / 17.0f;

    if (t < 256) {
        const float invn = 1.0f / (float)NN;
        const float mu  = asum[t] * invn;
        const float var = asum[512 + t] * invn - mu * mu;
        const float sc  = gamma[t] * rsqrtf(var + EPSF);
        ssS[t]       = sc;
        ssS[256 + t] = beta[t] - mu * sc;
    }
    __syncthreads();

    f32x4 acc[2][4] = {};   // [mi][ni]

    const int rg0 = wrapN(v0 - 16 + (t >> 3)),          f80 = (t & 7) * 8;
    const int rg1 = wrapN(v0 - 16 + ((1024 + t) >> 3)), f81 = ((1024 + t) & 7) * 8;
    const bool v1 = t < 128;

    u16x8 aq0 = *reinterpret_cast<const u16x8*>(A + (size_t)rg0 * 256 + f80);
    u16x8 aq1 = v1 ? *reinterpret_cast<const u16x8*>(A + (size_t)rg1 * 256 + f81)
                   : u16x8{};

    #pragma unroll
    for (int kt = 0; kt < 4; ++kt) {
        const int k0 = kt * 64;
        *reinterpret_cast<u16x8*>(xr + (t >> 3) * 160 + (t & 7) * 16)
            = bnrelu8(aq0, ssS, k0 + f80);
        if (v1)
            *reinterpret_cast<u16x8*>(xr + ((1024 + t) >> 3) * 160 + ((1024 + t) & 7) * 16)
                = bnrelu8(aq1, ssS, k0 + f81);
        __syncthreads();   // sync A
        #pragma unroll
        for (int it = 0; it < 2; ++it) {   // stage B(kt): 2048 chunks
            const int cb = (it * 16 + wave) * 64 + lane;
            const int row = cb >> 3;
            const int lk = (cb & 7) ^ (row & 7);
            GLD16(W2t + (size_t)row * 256 + k0 + lk * 8, Bs + (it * 16 + wave) * 1024);
        }
        // pass1: T4 sums
        t4_item(xr, t4, t >> 3, t & 7);
        if (v1) t4_item(xr, t4, 128 + (t >> 3), t & 7);
        __syncthreads();   // sync C
        // pass2: As via 5-tap combine
        as_item(xr, t4, As, t >> 3, t & 7, inv17);
        __syncthreads();   // sync B
        if (kt < 3) {
            const int k1 = k0 + 64;
            aq0 = *reinterpret_cast<const u16x8*>(A + (size_t)rg0 * 256 + k1 + f80);
            if (v1)
                aq1 = *reinterpret_cast<const u16x8*>(A + (size_t)rg1 * 256 + k1 + f81);
        }
        __builtin_amdgcn_s_setprio(1);
        #pragma unroll
        for (int kk = 0; kk < 2; ++kk) {
            const int klog = kk * 64 + ((lane >> 4) << 4);
            bf16x8 af[2];
            #pragma unroll
            for (int mi = 0; mi < 2; ++mi) {
                const int row = wr + mi * 16 + (lane & 15);
                af[mi] = *reinterpret_cast<const bf16x8*>(As + row * 128 + (klog ^ ((row & 7) << 4)));
            }
            #pragma unroll
            for (int ni = 0; ni < 4; ++ni) {
                const int rl = wc4 + ni * 16 + (lane & 15);
                const bf16x8 bv = *reinterpret_cast<const bf16x8*>(Bs + rl * 128 + (klog ^ ((rl & 7) << 4)));
                #pragma unroll
                for (int mi = 0; mi < 2; ++mi)
                    acc[mi][ni] = __builtin_amdgcn_mfma_f32_16x16x32_bf16(af[mi], bv, acc[mi][ni], 0, 0, 0);
            }
        }
        __builtin_amdgcn_s_setprio(0);
        // no trailing barrier
    }

    // epilogue: relu + per-row partial dots over this wave's 64 cols -> uW/wW
    float b2v[4], wav[4], wbv[4];
    #pragma unroll
    for (int ni = 0; ni < 4; ++ni) {
        const int col = wc4 + ni * 16 + (lane & 15);
        b2v[ni] = b2[col];
        wav[ni] = Wl[col];
        wbv[ni] = Wl[256 + col];
    }
    float* uW = (float*)smem;            // [4 col-groups][128 rows]
    float* wW = (float*)(smem + 2048);   // [4][128]
    float* uL = (float*)(smem + 23040);         // [128]
    float* wL = (float*)(smem + 23040 + 512);   // [128]
    float* PS = (float*)(smem + 23040 + 1024);  // [112]
    #pragma unroll
    for (int mi = 0; mi < 2; ++mi)
        #pragma unroll
        for (int r = 0; r < 4; ++r) {
            float pu = 0.f, pw = 0.f;
            #pragma unroll
            for (int ni = 0; ni < 4; ++ni) {
                const float hv = fmaxf(acc[mi][ni][r] + b2v[ni], 0.f);
                pu += hv * wav[ni];
                pw += hv * wbv[ni];
            }
            pu += __shfl_xor(pu, 1); pu += __shfl_xor(pu, 2);
            pu += __shfl_xor(pu, 4); pu += __shfl_xor(pu, 8);
            pw += __shfl_xor(pw, 1); pw += __shfl_xor(pw, 2);
            pw += __shfl_xor(pw, 4); pw += __shfl_xor(pw, 8);
            if ((lane & 15) == 0) {
                const int rl = wr + mi * 16 + ((lane >> 4) << 2) + r;
                uW[(wave & 3) * 128 + rl] = pu;
                wW[(wave & 3) * 128 + rl] = pw;
            }
        }
    __syncthreads();
    if (t < 128) {
        uL[t] = uW[t] + uW[128 + t] + uW[256 + t] + uW[384 + t];
        wL[t] = wW[t] + wW[128 + t] + wW[256 + t] + wW[384 + t];
    }
    __syncthreads();

    // P for nodes [v0, v0+112): PS[i] uses uL[i..i+16], wL[i+8]
    if (t < 112) {
        const int l = t + 8;
        float s = uL[l] + 16.0f * wL[l];
        #pragma unroll
        for (int o = 1; o <= 8; ++o)
            s += uL[l + o] + uL[l - o];
        PS[t] = s;
    }
    __syncthreads();

    // edge outputs for nodes [v0, v0+104)
    const float blv = bl[0];
    #pragma unroll
    for (int rr = 0; rr < 2; ++rr) {
        const int q = t + rr * 1024;             // [0, 2048); valid < 1664
        if (q >= 1664) continue;
        const int half = (q >= 832) ? 1 : 0;
        const int e = q - half * 832;
        const int i = e >> 3, off = e & 7;
        const int v = v0 + i;
        if (v >= NN) continue;
        if (!half) {   // forward edge (v -> v+1+off): P[v] + w[v+1+off]
            out[v * 8 + off] = sigmoidf_((PS[i] + wL[i + 9 + off]) * inv17 + blv);
        } else {       // reverse edge owned by tt = v: P[v+1+off] + w[v]
            out[NK + v * 8 + off] = sigmoidf_((PS[i + 1 + off] + wL[i + 8]) * inv17 + blv);
        }
    }
}

// ---------------- launch ----------------
extern "C" void kernel_launch(void* const* d_in, const int* in_sizes, int n_in,
                              void* d_out, int out_size, void* d_ws, size_t ws_size,
                              hipStream_t stream)
{
    const float* x      = (const float*)d_in[0];
    const float* W1     = (const float*)d_in[1];
    const float* b1     = (const float*)d_in[2];
    const float* gamma1 = (const float*)d_in[3];
    const float* beta1  = (const float*)d_in[4];
    const float* W2     = (const float*)d_in[5];
    const float* b2     = (const float*)d_in[6];
    const float* Wl     = (const float*)d_in[7];
    const float* bl     = (const float*)d_in[8];
    float* out = (float*)d_out;

    float*    asum = (float*)d_ws;                   // [1024]
    ushort*   A    = (ushort*)(asum + 1024);         // [NN,256] bf16
    ushort*   W1t  = A + (size_t)NN * 256;           // [256,128]
    ushort*   W2t  = W1t + 256 * 128;                // [256,256]

    k_prep  <<<49,   512,  0, stream>>>(W1, W2, W1t, W2t, asum);
    k_fused1<<<NT1B, 1024, 0, stream>>>(x, W1t, b1, A, asum);
    k_fused2<<<NT2B, 1024, 0, stream>>>(A, W2t, gamma1, beta1, b2, Wl, bl, asum, out);
}